// Round 2
// baseline (608.011 us; speedup 1.0000x reference)
//
#include <hip/hip_runtime.h>
#include <hip/hip_bf16.h>
#include <math.h>

#define NN 8192
#define DD 512
#define INV_T 14.285714285714286f   // 1/0.07 ; also the logits_max (diagonal) value

typedef __attribute__((ext_vector_type(8))) short s16x8;  // 8 bf16 = 4 VGPRs
typedef __attribute__((ext_vector_type(4))) float f32x4;
typedef __attribute__((ext_vector_type(4))) int   i32x4;

__device__ __forceinline__ unsigned short f32_to_bf16(float f) {
  unsigned int u = __float_as_uint(f);
  u += 0x7FFFu + ((u >> 16) & 1u);   // round-to-nearest-even
  return (unsigned short)(u >> 16);
}

__device__ __forceinline__ void async16(const void* g, void* l) {
  // 16B-wide global->LDS DMA; LDS dest must be wave-uniform base + lane*16
  __builtin_amdgcn_global_load_lds((__attribute__((address_space(1))) void*)(void*)g,
                                   (__attribute__((address_space(3))) void*)l,
                                   16, 0, 0);
}

// ---------------- Kernel A: normalize rows, emit bf16 (+ zero accumulators) ----
__global__ __launch_bounds__(256) void normalize_kernel(const float* __restrict__ f,
                                                        unsigned short* __restrict__ fnb,
                                                        float* __restrict__ acc) {
  // fold the 96KB accumulator memset into this kernel: 96 blocks x 256 floats
  if (blockIdx.x < 96) acc[blockIdx.x * 256 + threadIdx.x] = 0.f;

  const int wave = threadIdx.x >> 6;
  const int lane = threadIdx.x & 63;
  const int row  = blockIdx.x * 4 + wave;
  const float* src = f + (size_t)row * DD + lane * 8;
  float4 v0 = *(const float4*)src;
  float4 v1 = *(const float4*)(src + 4);
  float ss = v0.x*v0.x + v0.y*v0.y + v0.z*v0.z + v0.w*v0.w
           + v1.x*v1.x + v1.y*v1.y + v1.z*v1.z + v1.w*v1.w;
  #pragma unroll
  for (int o = 32; o; o >>= 1) ss += __shfl_xor(ss, o);
  const float r = 1.0f / fmaxf(sqrtf(ss), 1e-8f);
  ushort4 a, b;
  a.x = f32_to_bf16(v0.x * r); a.y = f32_to_bf16(v0.y * r);
  a.z = f32_to_bf16(v0.z * r); a.w = f32_to_bf16(v0.w * r);
  b.x = f32_to_bf16(v1.x * r); b.y = f32_to_bf16(v1.y * r);
  b.z = f32_to_bf16(v1.z * r); b.w = f32_to_bf16(v1.w * r);
  unsigned short* dst = fnb + (size_t)row * DD + lane * 8;
  *(ushort4*)dst = a;
  *(ushort4*)(dst + 4) = b;
}

// ---------------- Kernel B: single fused kernel ----------------
// 128x128 tile per block, 4 waves each 64x64 (4x4 of 16x16x32 bf16 MFMA).
// GEMM: coalesced async16 LDS staging. B-side uses R6's column permutation
// realized via an LDS ROW permutation L(brow) at staging time, so epilogue
// lane c16 owns sim columns 4*c16..4*c16+3 == one int4 of mask.
// NEW (this round): mask-tile L3 prefetch interleaved into K-iters 0..7 —
// one 4B touch per thread per iter covers all 2048 128B lines of the
// block's 256KB mask working set (both masks, both orientations). The
// __syncthreads vmcnt drain absorbs the latency; the point is that the
// 512MB chip-wide mask stream now runs DURING the GEMM phase instead of
// serially after it, and the epilogue's int4 loads hit L3.
__global__ __launch_bounds__(256, 3) void fused_kernel(const unsigned short* __restrict__ fnb,
                                                       const int* __restrict__ posm,
                                                       const int* __restrict__ negm,
                                                       float* __restrict__ Spos,
                                                       float* __restrict__ Sneg,
                                                       float* __restrict__ Pcnt) {
  // decode compact triangular block id -> (bi, bj), bi <= bj, 64x64 block grid
  const int bid = blockIdx.x;
  int bi = (int)(64.5 - sqrt(64.5 * 64.5 - 2.0 * (double)bid));
  while (64 * bi - bi * (bi - 1) / 2 > bid) --bi;
  while (64 * (bi + 1) - (bi + 1) * bi / 2 <= bid) ++bi;
  const int bj = bi + (bid - (64 * bi - bi * (bi - 1) / 2));
  const int I = bi * 128;
  const int J = bj * 128;
  const bool offdiag = (bi != bj);

  const int tid  = threadIdx.x;
  const int wave = tid >> 6;
  const int lane = tid & 63;
  const int wm = wave >> 1;            // 0..1 row half
  const int wn = wave & 1;             // 0..1 col half
  const int q   = lane >> 4;           // 0..3
  const int c16 = lane & 15;           // 0..15

  __shared__ alignas(16) unsigned short lA[128 * 32];
  __shared__ alignas(16) unsigned short lB[128 * 32];
  __shared__ float sacc[2][128][3];    // [panel][row][Spos,Sneg,Pcnt]
  for (int t = tid; t < 2 * 128 * 3; t += 256) ((float*)sacc)[t] = 0.f;

  // ---- GEMM ----
  f32x4 acc[4][4];
  const f32x4 z4 = {0.f, 0.f, 0.f, 0.f};
  #pragma unroll
  for (int mt = 0; mt < 4; ++mt)
    #pragma unroll
    for (int nt = 0; nt < 4; ++nt) acc[mt][nt] = z4;

  int pfsink = 0;   // keeps prefetch touch-loads live (rule: asm sink at end)

  for (int kk = 0; kk < DD / 32; ++kk) {
    const int k0 = kk * 32;
    #pragma unroll
    for (int c = 0; c < 2; ++c) {
      const int fidx = tid + c * 256;        // 0..511 16B-chunks
      const int L    = fidx >> 2;            // LDS row 0..127
      const int p    = fidx & 3;
      const int csrc = (p ^ ((L >> 1) & 3)) & 3;     // chunk XOR swizzle
      // lA: natural row order (R8-proven, 0 conflicts)
      async16(fnb + (size_t)(I + L) * DD + k0 + csrc * 8, (char*)lA + fidx * 16);
      // lB: row-permuted so MFMA B-reads (global row 4*c16+t) stay 2-way in banks
      const int gB = 4 * (L & 31) + (L >> 5);        // inverse of L(brow)
      async16(fnb + (size_t)(J + gB) * DD + k0 + csrc * 8, (char*)lB + fidx * 16);
    }

    // mask L3-warm prefetch: iters 0..7, one distinct 128B line per thread.
    // region = kk>>1 (wave-uniform): 0=pos direct, 1=neg direct,
    //          2=pos transposed, 3=neg transposed (skip 2,3 on diagonal).
    if (kk < 8) {
      const int reg  = kk >> 1;
      const int w    = ((kk & 1) << 8) | tid;     // 0..511 lines in region
      const int prow = w >> 2;                    // 0..127
      const int pcol = (w & 3) << 5;              // dword col of 128B line
      if (reg < 2 || offdiag) {
        const int rbase = (reg & 2) ? J : I;
        const int cbase = (reg & 2) ? I : J;
        const int* mp   = (reg & 1) ? negm : posm;
        pfsink += mp[(size_t)(rbase + prow) * NN + cbase + pcol];
      }
    }
    __syncthreads();

    s16x8 aF[4], bF[4];
    #pragma unroll
    for (int t = 0; t < 4; ++t) {
      const int arow = wm * 64 + t * 16 + c16;
      const int apos = (q ^ ((arow >> 1) & 3)) & 3;
      aF[t] = *(const s16x8*)((const char*)lA + arow * 64 + apos * 16);
      // want global row brow = wn*64 + 4*c16 + t  ->  LDS row L(brow)
      const int Lb = (wn * 16 + c16) | (t << 5);
      const int bpos = (q ^ ((Lb >> 1) & 3)) & 3;
      bF[t] = *(const s16x8*)((const char*)lB + Lb * 64 + bpos * 16);
    }
    #pragma unroll
    for (int mt = 0; mt < 4; ++mt)
      #pragma unroll
      for (int nt = 0; nt < 4; ++nt)
        acc[mt][nt] = __builtin_amdgcn_mfma_f32_16x16x32_bf16(aF[mt], bF[nt], acc[mt][nt], 0, 0, 0);
    __syncthreads();
  }

  asm volatile("" :: "v"(pfsink));   // keep prefetch loads live, no DCE

  // ---- epilogue ----
  // acc[mt][nt][r] = sim[I + wm*64 + mt*16 + q*4 + r][J + wn*64 + 4*c16 + nt]
  #pragma unroll
  for (int mt = 0; mt < 4; ++mt)
    #pragma unroll
    for (int nt = 0; nt < 4; ++nt)
      #pragma unroll
      for (int r = 0; r < 4; ++r)
        acc[mt][nt][r] = __expf(acc[mt][nt][r] * INV_T - INV_T);

  const bool hasdiag = (bi == bj) && (wm == wn);
  const int cb = wn * 64 + 4 * c16;            // local col base (this lane's int4)

  // direct pass: rows I.., cols J.. ; 1KB/wave-instr coalesced int4 loads
  #pragma unroll
  for (int mt = 0; mt < 4; ++mt) {
    const int rl = wm * 64 + mt * 16 + q * 4;  // local row base
    i32x4 pv[4], nv[4];
    #pragma unroll
    for (int r = 0; r < 4; ++r) {
      const size_t off = (size_t)(I + rl + r) * NN + J + cb;
      pv[r] = __builtin_nontemporal_load((const i32x4*)(posm + off));
      nv[r] = __builtin_nontemporal_load((const i32x4*)(negm + off));
    }
    #pragma unroll
    for (int r = 0; r < 4; ++r) {
      float dsp = 0.f, dsn = 0.f, dpc = 0.f;
      #pragma unroll
      for (int nt = 0; nt < 4; ++nt) {
        float pf = (float)pv[r][nt];
        float nf = (float)nv[r][nt];
        if (hasdiag && (rl + r == cb + nt)) { pf = 0.f; nf = 0.f; }  // self-contrast diag
        const float e = acc[mt][nt][r];
        dsp = fmaf(e, pf, dsp);
        dsn = fmaf(e, nf, dsn);
        dpc += pf;
      }
      #pragma unroll
      for (int o = 1; o <= 8; o <<= 1) {
        dsp += __shfl_xor(dsp, o);
        dsn += __shfl_xor(dsn, o);
        dpc += __shfl_xor(dpc, o);
      }
      if (c16 == 0) {   // LDS atomics: lgkmcnt only
        atomicAdd(&sacc[0][rl + r][0], dsp);
        atomicAdd(&sacc[0][rl + r][1], dsn);
        atomicAdd(&sacc[0][rl + r][2], dpc);
      }
    }
  }

  // transposed pass: sim(col,row) == sim(row,col); rows J.., cols I..
  if (offdiag) {
    #pragma unroll
    for (int nt = 0; nt < 4; ++nt) {
      const int trl = cb + nt;                 // local row in J-panel
      i32x4 pv[4], nv[4];
      #pragma unroll
      for (int mt = 0; mt < 4; ++mt) {
        const size_t off = (size_t)(J + trl) * NN + I + wm * 64 + mt * 16 + q * 4;
        pv[mt] = __builtin_nontemporal_load((const i32x4*)(posm + off));
        nv[mt] = __builtin_nontemporal_load((const i32x4*)(negm + off));
      }
      float ts = 0.f, tn = 0.f, tp = 0.f;
      #pragma unroll
      for (int mt = 0; mt < 4; ++mt) {
        #pragma unroll
        for (int r = 0; r < 4; ++r) {
          const float e = acc[mt][nt][r];
          ts = fmaf(e, (float)pv[mt][r], ts);
          tn = fmaf(e, (float)nv[mt][r], tn);
          tp += (float)pv[mt][r];
        }
      }
      ts += __shfl_xor(ts, 16); ts += __shfl_xor(ts, 32);
      tn += __shfl_xor(tn, 16); tn += __shfl_xor(tn, 32);
      tp += __shfl_xor(tp, 16); tp += __shfl_xor(tp, 32);
      if (q == 0) {
        atomicAdd(&sacc[1][trl][0], ts);
        atomicAdd(&sacc[1][trl][1], tn);
        atomicAdd(&sacc[1][trl][2], tp);
      }
    }
  }

  __syncthreads();

  // one batch of global atomics at the very end; nothing waits on them
  const int r = tid & 127;
  if (tid < 128) {
    atomicAdd(&Spos[I + r], sacc[0][r][0]);
    atomicAdd(&Sneg[I + r], sacc[0][r][1]);
    atomicAdd(&Pcnt[I + r], sacc[0][r][2]);
  } else if (offdiag) {
    atomicAdd(&Spos[J + r], sacc[1][r][0]);
    atomicAdd(&Sneg[J + r], sacc[1][r][1]);
    atomicAdd(&Pcnt[J + r], sacc[1][r][2]);
  }
}

// ---------------- Kernel C: finalize ----------------
__global__ __launch_bounds__(256) void finalize_kernel(const float* __restrict__ Spos,
                                                       const float* __restrict__ Sneg,
                                                       const float* __restrict__ Pcnt,
                                                       float* __restrict__ out) {
  float local = 0.f;
  for (int i = threadIdx.x; i < NN; i += 256) {
    const float sp = Spos[i], sn = Sneg[i], pc = Pcnt[i];
    const float card = (pc == 0.f) ? 1.f : pc;
    local += (logf(sn) * pc - sp) / card;
  }
  #pragma unroll
  for (int o = 32; o; o >>= 1) local += __shfl_xor(local, o);
  __shared__ float red[4];
  if ((threadIdx.x & 63) == 0) red[threadIdx.x >> 6] = local;
  __syncthreads();
  if (threadIdx.x == 0)
    out[0] = (red[0] + red[1] + red[2] + red[3]) * (1.0f / (float)NN);
}

extern "C" void kernel_launch(void* const* d_in, const int* in_sizes, int n_in,
                              void* d_out, int out_size, void* d_ws, size_t ws_size,
                              hipStream_t stream) {
  const float* feat = (const float*)d_in[0];
  const int* posm   = (const int*)d_in[1];
  const int* negm   = (const int*)d_in[2];
  float* out = (float*)d_out;

  char* ws = (char*)d_ws;
  unsigned short* fnb = (unsigned short*)ws;                 // 8 MB
  float* Spos = (float*)(ws + (size_t)8 * 1024 * 1024);
  float* Sneg = Spos + NN;
  float* Pcnt = Sneg + NN;

  normalize_kernel<<<NN / 4, 256, 0, stream>>>(feat, fnb, Spos);
  fused_kernel<<<2080, 256, 0, stream>>>(fnb, posm, negm, Spos, Sneg, Pcnt);
  finalize_kernel<<<1, 256, 0, stream>>>(Spos, Sneg, Pcnt, out);
}

// Round 3
// 584.396 us; speedup vs baseline: 1.0404x; 1.0404x over previous
//
#include <hip/hip_runtime.h>
#include <hip/hip_bf16.h>
#include <math.h>

#define NN 8192
#define DD 512
#define INV_T 14.285714285714286f   // 1/0.07 ; also the logits_max (diagonal) value

typedef __attribute__((ext_vector_type(8))) short s16x8;  // 8 bf16 = 4 VGPRs
typedef __attribute__((ext_vector_type(4))) float f32x4;
typedef __attribute__((ext_vector_type(4))) int   i32x4;

__device__ __forceinline__ unsigned short f32_to_bf16(float f) {
  unsigned int u = __float_as_uint(f);
  u += 0x7FFFu + ((u >> 16) & 1u);   // round-to-nearest-even
  return (unsigned short)(u >> 16);
}

__device__ __forceinline__ void async16(const void* g, void* l) {
  // 16B-wide global->LDS DMA; LDS dest must be wave-uniform base + lane*16
  __builtin_amdgcn_global_load_lds((__attribute__((address_space(1))) void*)(void*)g,
                                   (__attribute__((address_space(3))) void*)l,
                                   16, 0, 0);
}

// ---------------- Kernel A: normalize rows, emit bf16 (+ zero accumulators) ----
__global__ __launch_bounds__(256) void normalize_kernel(const float* __restrict__ f,
                                                        unsigned short* __restrict__ fnb,
                                                        float* __restrict__ acc) {
  // fold the 96KB accumulator memset into this kernel: 96 blocks x 256 floats
  if (blockIdx.x < 96) acc[blockIdx.x * 256 + threadIdx.x] = 0.f;

  const int wave = threadIdx.x >> 6;
  const int lane = threadIdx.x & 63;
  const int row  = blockIdx.x * 4 + wave;
  const float* src = f + (size_t)row * DD + lane * 8;
  float4 v0 = *(const float4*)src;
  float4 v1 = *(const float4*)(src + 4);
  float ss = v0.x*v0.x + v0.y*v0.y + v0.z*v0.z + v0.w*v0.w
           + v1.x*v1.x + v1.y*v1.y + v1.z*v1.z + v1.w*v1.w;
  #pragma unroll
  for (int o = 32; o; o >>= 1) ss += __shfl_xor(ss, o);
  const float r = 1.0f / fmaxf(sqrtf(ss), 1e-8f);
  ushort4 a, b;
  a.x = f32_to_bf16(v0.x * r); a.y = f32_to_bf16(v0.y * r);
  a.z = f32_to_bf16(v0.z * r); a.w = f32_to_bf16(v0.w * r);
  b.x = f32_to_bf16(v1.x * r); b.y = f32_to_bf16(v1.y * r);
  b.z = f32_to_bf16(v1.z * r); b.w = f32_to_bf16(v1.w * r);
  unsigned short* dst = fnb + (size_t)row * DD + lane * 8;
  *(ushort4*)dst = a;
  *(ushort4*)(dst + 4) = b;
}

// ---------------- Kernel B: single fused kernel ----------------
// 128x128 tile per block, 4 waves each 64x64 (4x4 of 16x16x32 bf16 MFMA).
// R2 post-mortem: per-iteration L3 touch-prefetch REVERTED (barrier vmcnt(0)
// drained cold gathers 8x per block -> fused 150->224us).
// R3: occupancy 3->4 blocks/CU. Cap was unified regs: 80 VGPR + 64 AGPR = 144
// -> 3 waves/SIMD. Cut to <=128 via (a) bF ping-pong (2 regs not 4),
// (b) epilogue mask loads in half-groups of 2 rows (peak 16 not 32 regs),
// (c) __launch_bounds__(256,4). More resident blocks -> cross-phase overlap
// (one block's mask-stream epilogue overlaps another's GEMM) + more TLP for
// the cold mask loads.
__global__ __launch_bounds__(256, 4) void fused_kernel(const unsigned short* __restrict__ fnb,
                                                       const int* __restrict__ posm,
                                                       const int* __restrict__ negm,
                                                       float* __restrict__ Spos,
                                                       float* __restrict__ Sneg,
                                                       float* __restrict__ Pcnt) {
  // decode compact triangular block id -> (bi, bj), bi <= bj, 64x64 block grid
  const int bid = blockIdx.x;
  int bi = (int)(64.5 - sqrt(64.5 * 64.5 - 2.0 * (double)bid));
  while (64 * bi - bi * (bi - 1) / 2 > bid) --bi;
  while (64 * (bi + 1) - (bi + 1) * bi / 2 <= bid) ++bi;
  const int bj = bi + (bid - (64 * bi - bi * (bi - 1) / 2));
  const int I = bi * 128;
  const int J = bj * 128;
  const bool offdiag = (bi != bj);

  const int tid  = threadIdx.x;
  const int wave = tid >> 6;
  const int lane = tid & 63;
  const int wm = wave >> 1;            // 0..1 row half
  const int wn = wave & 1;             // 0..1 col half
  const int q   = lane >> 4;           // 0..3
  const int c16 = lane & 15;           // 0..15

  __shared__ alignas(16) unsigned short lA[128 * 32];
  __shared__ alignas(16) unsigned short lB[128 * 32];
  __shared__ float sacc[2][128][3];    // [panel][row][Spos,Sneg,Pcnt]
  for (int t = tid; t < 2 * 128 * 3; t += 256) ((float*)sacc)[t] = 0.f;

  // ---- GEMM ----
  f32x4 acc[4][4];
  const f32x4 z4 = {0.f, 0.f, 0.f, 0.f};
  #pragma unroll
  for (int mt = 0; mt < 4; ++mt)
    #pragma unroll
    for (int nt = 0; nt < 4; ++nt) acc[mt][nt] = z4;

  for (int kk = 0; kk < DD / 32; ++kk) {
    const int k0 = kk * 32;
    #pragma unroll
    for (int c = 0; c < 2; ++c) {
      const int fidx = tid + c * 256;        // 0..511 16B-chunks
      const int L    = fidx >> 2;            // LDS row 0..127
      const int p    = fidx & 3;
      const int csrc = (p ^ ((L >> 1) & 3)) & 3;     // chunk XOR swizzle
      // lA: natural row order (R8-proven, 0 conflicts)
      async16(fnb + (size_t)(I + L) * DD + k0 + csrc * 8, (char*)lA + fidx * 16);
      // lB: row-permuted so MFMA B-reads (global row 4*c16+t) stay 2-way in banks
      const int gB = 4 * (L & 31) + (L >> 5);        // inverse of L(brow)
      async16(fnb + (size_t)(J + gB) * DD + k0 + csrc * 8, (char*)lB + fidx * 16);
    }
    __syncthreads();

    s16x8 aF[4];
    #pragma unroll
    for (int t = 0; t < 4; ++t) {
      const int arow = wm * 64 + t * 16 + c16;
      const int apos = (q ^ ((arow >> 1) & 3)) & 3;
      aF[t] = *(const s16x8*)((const char*)lA + arow * 64 + apos * 16);
    }
    // bF ping-pong: 2 live B-fragments instead of 4 (-8 VGPR)
    s16x8 bcur, bnxt;
    {
      const int Lb = (wn * 16 + c16);            // nt=0 -> t bits = 0
      const int bpos = (q ^ ((Lb >> 1) & 3)) & 3;
      bcur = *(const s16x8*)((const char*)lB + Lb * 64 + bpos * 16);
    }
    #pragma unroll
    for (int nt = 0; nt < 4; ++nt) {
      if (nt < 3) {
        const int Lb = (wn * 16 + c16) | ((nt + 1) << 5);
        const int bpos = (q ^ ((Lb >> 1) & 3)) & 3;
        bnxt = *(const s16x8*)((const char*)lB + Lb * 64 + bpos * 16);
      }
      #pragma unroll
      for (int mt = 0; mt < 4; ++mt)
        acc[mt][nt] = __builtin_amdgcn_mfma_f32_16x16x32_bf16(aF[mt], bcur, acc[mt][nt], 0, 0, 0);
      bcur = bnxt;
    }
    __syncthreads();
  }

  // ---- epilogue ----
  // acc[mt][nt][r] = sim[I + wm*64 + mt*16 + q*4 + r][J + wn*64 + 4*c16 + nt]
  #pragma unroll
  for (int mt = 0; mt < 4; ++mt)
    #pragma unroll
    for (int nt = 0; nt < 4; ++nt)
      #pragma unroll
      for (int r = 0; r < 4; ++r)
        acc[mt][nt][r] = __expf(acc[mt][nt][r] * INV_T - INV_T);

  const bool hasdiag = (bi == bj) && (wm == wn);
  const int cb = wn * 64 + 4 * c16;            // local col base (this lane's int4)

  // direct pass: rows I.., cols J.. ; coalesced int4 loads, 2 rows per
  // half-group (peak 4 loads/16 regs in flight; occupancy covers latency)
  #pragma unroll
  for (int mt = 0; mt < 4; ++mt) {
    const int rl = wm * 64 + mt * 16 + q * 4;  // local row base
    #pragma unroll
    for (int h = 0; h < 2; ++h) {
      i32x4 pv[2], nv[2];
      #pragma unroll
      for (int u = 0; u < 2; ++u) {
        const int r = 2 * h + u;
        const size_t off = (size_t)(I + rl + r) * NN + J + cb;
        pv[u] = __builtin_nontemporal_load((const i32x4*)(posm + off));
        nv[u] = __builtin_nontemporal_load((const i32x4*)(negm + off));
      }
      #pragma unroll
      for (int u = 0; u < 2; ++u) {
        const int r = 2 * h + u;
        float dsp = 0.f, dsn = 0.f, dpc = 0.f;
        #pragma unroll
        for (int nt = 0; nt < 4; ++nt) {
          float pf = (float)pv[u][nt];
          float nf = (float)nv[u][nt];
          if (hasdiag && (rl + r == cb + nt)) { pf = 0.f; nf = 0.f; }  // self-contrast diag
          const float e = acc[mt][nt][r];
          dsp = fmaf(e, pf, dsp);
          dsn = fmaf(e, nf, dsn);
          dpc += pf;
        }
        #pragma unroll
        for (int o = 1; o <= 8; o <<= 1) {
          dsp += __shfl_xor(dsp, o);
          dsn += __shfl_xor(dsn, o);
          dpc += __shfl_xor(dpc, o);
        }
        if (c16 == 0) {   // LDS atomics: lgkmcnt only
          atomicAdd(&sacc[0][rl + r][0], dsp);
          atomicAdd(&sacc[0][rl + r][1], dsn);
          atomicAdd(&sacc[0][rl + r][2], dpc);
        }
      }
    }
  }

  // transposed pass: sim(col,row) == sim(row,col); rows J.., cols I..
  if (offdiag) {
    #pragma unroll
    for (int nt = 0; nt < 4; ++nt) {
      const int trl = cb + nt;                 // local row in J-panel
      float ts = 0.f, tn = 0.f, tp = 0.f;
      #pragma unroll
      for (int h = 0; h < 2; ++h) {
        i32x4 pv[2], nv[2];
        #pragma unroll
        for (int u = 0; u < 2; ++u) {
          const int mt = 2 * h + u;
          const size_t off = (size_t)(J + trl) * NN + I + wm * 64 + mt * 16 + q * 4;
          pv[u] = __builtin_nontemporal_load((const i32x4*)(posm + off));
          nv[u] = __builtin_nontemporal_load((const i32x4*)(negm + off));
        }
        #pragma unroll
        for (int u = 0; u < 2; ++u) {
          const int mt = 2 * h + u;
          #pragma unroll
          for (int r = 0; r < 4; ++r) {
            const float e = acc[mt][nt][r];
            ts = fmaf(e, (float)pv[u][r], ts);
            tn = fmaf(e, (float)nv[u][r], tn);
            tp += (float)pv[u][r];
          }
        }
      }
      ts += __shfl_xor(ts, 16); ts += __shfl_xor(ts, 32);
      tn += __shfl_xor(tn, 16); tn += __shfl_xor(tn, 32);
      tp += __shfl_xor(tp, 16); tp += __shfl_xor(tp, 32);
      if (q == 0) {
        atomicAdd(&sacc[1][trl][0], ts);
        atomicAdd(&sacc[1][trl][1], tn);
        atomicAdd(&sacc[1][trl][2], tp);
      }
    }
  }

  __syncthreads();

  // one batch of global atomics at the very end; nothing waits on them
  const int r = tid & 127;
  if (tid < 128) {
    atomicAdd(&Spos[I + r], sacc[0][r][0]);
    atomicAdd(&Sneg[I + r], sacc[0][r][1]);
    atomicAdd(&Pcnt[I + r], sacc[0][r][2]);
  } else if (offdiag) {
    atomicAdd(&Spos[J + r], sacc[1][r][0]);
    atomicAdd(&Sneg[J + r], sacc[1][r][1]);
    atomicAdd(&Pcnt[J + r], sacc[1][r][2]);
  }
}

// ---------------- Kernel C: finalize ----------------
__global__ __launch_bounds__(256) void finalize_kernel(const float* __restrict__ Spos,
                                                       const float* __restrict__ Sneg,
                                                       const float* __restrict__ Pcnt,
                                                       float* __restrict__ out) {
  float local = 0.f;
  for (int i = threadIdx.x; i < NN; i += 256) {
    const float sp = Spos[i], sn = Sneg[i], pc = Pcnt[i];
    const float card = (pc == 0.f) ? 1.f : pc;
    local += (logf(sn) * pc - sp) / card;
  }
  #pragma unroll
  for (int o = 32; o; o >>= 1) local += __shfl_xor(local, o);
  __shared__ float red[4];
  if ((threadIdx.x & 63) == 0) red[threadIdx.x >> 6] = local;
  __syncthreads();
  if (threadIdx.x == 0)
    out[0] = (red[0] + red[1] + red[2] + red[3]) * (1.0f / (float)NN);
}

extern "C" void kernel_launch(void* const* d_in, const int* in_sizes, int n_in,
                              void* d_out, int out_size, void* d_ws, size_t ws_size,
                              hipStream_t stream) {
  const float* feat = (const float*)d_in[0];
  const int* posm   = (const int*)d_in[1];
  const int* negm   = (const int*)d_in[2];
  float* out = (float*)d_out;

  char* ws = (char*)d_ws;
  unsigned short* fnb = (unsigned short*)ws;                 // 8 MB
  float* Spos = (float*)(ws + (size_t)8 * 1024 * 1024);
  float* Sneg = Spos + NN;
  float* Pcnt = Sneg + NN;

  normalize_kernel<<<NN / 4, 256, 0, stream>>>(feat, fnb, Spos);
  fused_kernel<<<2080, 256, 0, stream>>>(fnb, posm, negm, Spos, Sneg, Pcnt);
  finalize_kernel<<<1, 256, 0, stream>>>(Spos, Sneg, Pcnt, out);
}

// Round 4
// 568.588 us; speedup vs baseline: 1.0693x; 1.0278x over previous
//
#include <hip/hip_runtime.h>
#include <hip/hip_bf16.h>
#include <math.h>

#define NN 8192
#define DD 512
#define INV_T 14.285714285714286f   // 1/0.07 ; also the logits_max (diagonal) value

typedef __attribute__((ext_vector_type(8))) short s16x8;  // 8 bf16 = 4 VGPRs
typedef __attribute__((ext_vector_type(4))) float f32x4;

__device__ __forceinline__ unsigned short f32_to_bf16(float f) {
  unsigned int u = __float_as_uint(f);
  u += 0x7FFFu + ((u >> 16) & 1u);   // round-to-nearest-even
  return (unsigned short)(u >> 16);
}

__device__ __forceinline__ void async16(const void* g, void* l) {
  // 16B-wide global->LDS DMA; LDS dest must be wave-uniform base + lane*16
  __builtin_amdgcn_global_load_lds((__attribute__((address_space(1))) void*)(void*)g,
                                   (__attribute__((address_space(3))) void*)l,
                                   16, 0, 0);
}

// ---------------- Kernel A: normalize rows, emit bf16 (+ zero accumulators) ----
__global__ __launch_bounds__(256) void normalize_kernel(const float* __restrict__ f,
                                                        unsigned short* __restrict__ fnb,
                                                        float* __restrict__ acc) {
  // fold the 96KB accumulator memset into this kernel: 96 blocks x 256 floats
  if (blockIdx.x < 96) acc[blockIdx.x * 256 + threadIdx.x] = 0.f;

  const int wave = threadIdx.x >> 6;
  const int lane = threadIdx.x & 63;
  const int row  = blockIdx.x * 4 + wave;
  const float* src = f + (size_t)row * DD + lane * 8;
  float4 v0 = *(const float4*)src;
  float4 v1 = *(const float4*)(src + 4);
  float ss = v0.x*v0.x + v0.y*v0.y + v0.z*v0.z + v0.w*v0.w
           + v1.x*v1.x + v1.y*v1.y + v1.z*v1.z + v1.w*v1.w;
  #pragma unroll
  for (int o = 32; o; o >>= 1) ss += __shfl_xor(ss, o);
  const float r = 1.0f / fmaxf(sqrtf(ss), 1e-8f);
  ushort4 a, b;
  a.x = f32_to_bf16(v0.x * r); a.y = f32_to_bf16(v0.y * r);
  a.z = f32_to_bf16(v0.z * r); a.w = f32_to_bf16(v0.w * r);
  b.x = f32_to_bf16(v1.x * r); b.y = f32_to_bf16(v1.y * r);
  b.z = f32_to_bf16(v1.z * r); b.w = f32_to_bf16(v1.w * r);
  unsigned short* dst = fnb + (size_t)row * DD + lane * 8;
  *(ushort4*)dst = a;
  *(ushort4*)(dst + 4) = b;
}

// ---------------- Kernel B: single fused kernel ----------------
// 128x128 tile per block, 4 waves each 64x64 (4x4 of 16x16x32 bf16 MFMA).
// R4 restructure: masks (0/1 ints) are streamed DURING the 16 K-iterations
// and bit-packed into LDS via __ballot. Per iter: one kind (pos/neg x
// direct/transposed) x one 32-row slice = 16KB raw -> 512B of bits. Loads
// issue at the TOP of the compute phase (after barrier 1), are consumed by
// ballots AFTER the MFMAs (progressive vmcnt, ~full MFMA phase of latency
// cover) — R2 lesson: never issue vmem right before a barrier drain.
// Epilogue has ZERO global loads: bits from LDS, pure VALU. Mask HBM stream
// (512MB chip-wide) thus overlaps the GEMM instead of serializing after it.
__global__ __launch_bounds__(256, 3) void fused_kernel(const unsigned short* __restrict__ fnb,
                                                       const int* __restrict__ posm,
                                                       const int* __restrict__ negm,
                                                       float* __restrict__ Spos,
                                                       float* __restrict__ Sneg,
                                                       float* __restrict__ Pcnt) {
  // decode compact triangular block id -> (bi, bj), bi <= bj, 64x64 block grid
  const int bid = blockIdx.x;
  int bi = (int)(64.5 - sqrt(64.5 * 64.5 - 2.0 * (double)bid));
  while (64 * bi - bi * (bi - 1) / 2 > bid) --bi;
  while (64 * (bi + 1) - (bi + 1) * bi / 2 <= bid) ++bi;
  const int bj = bi + (bid - (64 * bi - bi * (bi - 1) / 2));
  const int I = bi * 128;
  const int J = bj * 128;
  const bool offdiag = (bi != bj);

  const int tid  = threadIdx.x;
  const int wave = tid >> 6;
  const int lane = tid & 63;
  const int wm = wave >> 1;            // 0..1 row half
  const int wn = wave & 1;             // 0..1 col half
  const int q   = lane >> 4;           // 0..3
  const int c16 = lane & 15;           // 0..15

  __shared__ alignas(16) unsigned short lA[128 * 32];
  __shared__ alignas(16) unsigned short lB[128 * 32];
  __shared__ float sacc[2][128][3];    // [panel][row][Spos,Sneg,Pcnt]
  // packed mask bits: [kind][row][word64]; kind 0=posD 1=negD 2=posT 3=negT
  __shared__ unsigned long long pk[4][128][2];
  for (int t = tid; t < 2 * 128 * 3; t += 256) ((float*)sacc)[t] = 0.f;

  // ---- GEMM + mask bit-pack stream ----
  f32x4 acc[4][4];
  const f32x4 z4 = {0.f, 0.f, 0.f, 0.f};
  #pragma unroll
  for (int mt = 0; mt < 4; ++mt)
    #pragma unroll
    for (int nt = 0; nt < 4; ++nt) acc[mt][nt] = z4;

  for (int kk = 0; kk < DD / 32; ++kk) {
    const int k0 = kk * 32;
    #pragma unroll
    for (int c = 0; c < 2; ++c) {
      const int fidx = tid + c * 256;        // 0..511 16B-chunks
      const int L    = fidx >> 2;            // LDS row 0..127
      const int p    = fidx & 3;
      const int csrc = (p ^ ((L >> 1) & 3)) & 3;     // chunk XOR swizzle
      // lA: natural row order (R8-proven, 0 conflicts)
      async16(fnb + (size_t)(I + L) * DD + k0 + csrc * 8, (char*)lA + fidx * 16);
      // lB: row-permuted so MFMA B-reads (global row 4*c16+t) stay 2-way in banks
      const int gB = 4 * (L & 31) + (L >> 5);        // inverse of L(brow)
      async16(fnb + (size_t)(J + gB) * DD + k0 + csrc * 8, (char*)lB + fidx * 16);
    }
    __syncthreads();   // drains staging; nothing else outstanding

    // mask tile loads for this iter: kind kd, 32-row slice, wave w owns 8 rows.
    // 16 coalesced 256B wave-loads per wave; consumed by ballots after MFMA.
    const int kd    = kk & 3;
    const int slice = kk >> 2;
    const bool mact = (kd < 2) || offdiag;   // block-uniform
    int mv[16];
    if (mact) {
      const int rbase = (kd & 2) ? J : I;
      const int cbase = (kd & 2) ? I : J;
      const int* __restrict__ mp = (kd & 1) ? negm : posm;
      const int trow0 = slice * 32 + wave * 8;
      #pragma unroll
      for (int j = 0; j < 16; ++j) {
        const int trow = trow0 + (j >> 1);
        mv[j] = mp[(size_t)(rbase + trow) * NN + cbase + (j & 1) * 64 + lane];
      }
    }

    s16x8 aF[4], bF[4];
    #pragma unroll
    for (int t = 0; t < 4; ++t) {
      const int arow = wm * 64 + t * 16 + c16;
      const int apos = (q ^ ((arow >> 1) & 3)) & 3;
      aF[t] = *(const s16x8*)((const char*)lA + arow * 64 + apos * 16);
      // want global row brow = wn*64 + 4*c16 + t  ->  LDS row L(brow)
      const int Lb = (wn * 16 + c16) | (t << 5);
      const int bpos = (q ^ ((Lb >> 1) & 3)) & 3;
      bF[t] = *(const s16x8*)((const char*)lB + Lb * 64 + bpos * 16);
    }
    #pragma unroll
    for (int mt = 0; mt < 4; ++mt)
      #pragma unroll
      for (int nt = 0; nt < 4; ++nt)
        acc[mt][nt] = __builtin_amdgcn_mfma_f32_16x16x32_bf16(aF[mt], bF[nt], acc[mt][nt], 0, 0, 0);

    // ballots: progressive vmcnt waits, fully covered by frag reads + MFMA
    if (mact) {
      const int trow0 = slice * 32 + wave * 8;
      #pragma unroll
      for (int j = 0; j < 16; ++j) {
        const unsigned long long b = __ballot(mv[j] != 0);
        if (lane == j) pk[kd][trow0 + (j >> 1)][j & 1] = b;
      }
    }
    __syncthreads();
  }

  // ---- epilogue: pure LDS/VALU, no global loads ----
  // acc[mt][nt][r] = sim[I + wm*64 + mt*16 + q*4 + r][J + wn*64 + 4*c16 + nt]
  #pragma unroll
  for (int mt = 0; mt < 4; ++mt)
    #pragma unroll
    for (int nt = 0; nt < 4; ++nt)
      #pragma unroll
      for (int r = 0; r < 4; ++r)
        acc[mt][nt][r] = __expf(acc[mt][nt][r] * INV_T - INV_T);

  const bool hasdiag = (bi == bj) && (wm == wn);
  const int cb = wn * 64 + 4 * c16;            // local col base
  const int half = c16 >> 3;                   // which 32b half of the 64b word
  const int bsh  = 4 * (c16 & 7);              // bit base within the half

  // direct pass: rows I.., cols J..
  #pragma unroll
  for (int mt = 0; mt < 4; ++mt) {
    const int rl = wm * 64 + mt * 16 + q * 4;  // local row base
    #pragma unroll
    for (int r = 0; r < 4; ++r) {
      const int row = rl + r;
      const uint2 pw = *(const uint2*)&pk[0][row][wn];
      const uint2 nw = *(const uint2*)&pk[1][row][wn];
      const unsigned int p32 = half ? pw.y : pw.x;
      const unsigned int n32 = half ? nw.y : nw.x;
      float dsp = 0.f, dsn = 0.f, dpc = 0.f;
      #pragma unroll
      for (int nt = 0; nt < 4; ++nt) {
        float pf = (float)((p32 >> (bsh + nt)) & 1u);
        float nf = (float)((n32 >> (bsh + nt)) & 1u);
        if (hasdiag && (row == cb + nt)) { pf = 0.f; nf = 0.f; }  // self-contrast diag
        const float e = acc[mt][nt][r];
        dsp = fmaf(e, pf, dsp);
        dsn = fmaf(e, nf, dsn);
        dpc += pf;
      }
      #pragma unroll
      for (int o = 1; o <= 8; o <<= 1) {
        dsp += __shfl_xor(dsp, o);
        dsn += __shfl_xor(dsn, o);
        dpc += __shfl_xor(dpc, o);
      }
      if (c16 == 0) {   // LDS atomics: lgkmcnt only
        atomicAdd(&sacc[0][row][0], dsp);
        atomicAdd(&sacc[0][row][1], dsn);
        atomicAdd(&sacc[0][row][2], dpc);
      }
    }
  }

  // transposed pass: sim(col,row) == sim(row,col); rows J.., cols I..
  if (offdiag) {
    #pragma unroll
    for (int nt = 0; nt < 4; ++nt) {
      const int trl = cb + nt;                 // local row in J-panel
      const uint2 pw = *(const uint2*)&pk[2][trl][wm];
      const uint2 nw = *(const uint2*)&pk[3][trl][wm];
      float ts = 0.f, tn = 0.f, tp = 0.f;
      #pragma unroll
      for (int mt = 0; mt < 4; ++mt) {
        const unsigned int p32 = (mt < 2) ? pw.x : pw.y;
        const unsigned int n32 = (mt < 2) ? nw.x : nw.y;
        #pragma unroll
        for (int r = 0; r < 4; ++r) {
          const int bit = (mt & 1) * 16 + q * 4 + r;
          const float pf = (float)((p32 >> bit) & 1u);
          const float nf = (float)((n32 >> bit) & 1u);
          const float e = acc[mt][nt][r];
          ts = fmaf(e, pf, ts);
          tn = fmaf(e, nf, tn);
          tp += pf;
        }
      }
      ts += __shfl_xor(ts, 16); ts += __shfl_xor(ts, 32);
      tn += __shfl_xor(tn, 16); tn += __shfl_xor(tn, 32);
      tp += __shfl_xor(tp, 16); tp += __shfl_xor(tp, 32);
      if (q == 0) {
        atomicAdd(&sacc[1][trl][0], ts);
        atomicAdd(&sacc[1][trl][1], tn);
        atomicAdd(&sacc[1][trl][2], tp);
      }
    }
  }

  __syncthreads();

  // one batch of global atomics at the very end; nothing waits on them
  const int r = tid & 127;
  if (tid < 128) {
    atomicAdd(&Spos[I + r], sacc[0][r][0]);
    atomicAdd(&Sneg[I + r], sacc[0][r][1]);
    atomicAdd(&Pcnt[I + r], sacc[0][r][2]);
  } else if (offdiag) {
    atomicAdd(&Spos[J + r], sacc[1][r][0]);
    atomicAdd(&Sneg[J + r], sacc[1][r][1]);
    atomicAdd(&Pcnt[J + r], sacc[1][r][2]);
  }
}

// ---------------- Kernel C: finalize ----------------
__global__ __launch_bounds__(256) void finalize_kernel(const float* __restrict__ Spos,
                                                       const float* __restrict__ Sneg,
                                                       const float* __restrict__ Pcnt,
                                                       float* __restrict__ out) {
  float local = 0.f;
  for (int i = threadIdx.x; i < NN; i += 256) {
    const float sp = Spos[i], sn = Sneg[i], pc = Pcnt[i];
    const float card = (pc == 0.f) ? 1.f : pc;
    local += (logf(sn) * pc - sp) / card;
  }
  #pragma unroll
  for (int o = 32; o; o >>= 1) local += __shfl_xor(local, o);
  __shared__ float red[4];
  if ((threadIdx.x & 63) == 0) red[threadIdx.x >> 6] = local;
  __syncthreads();
  if (threadIdx.x == 0)
    out[0] = (red[0] + red[1] + red[2] + red[3]) * (1.0f / (float)NN);
}

extern "C" void kernel_launch(void* const* d_in, const int* in_sizes, int n_in,
                              void* d_out, int out_size, void* d_ws, size_t ws_size,
                              hipStream_t stream) {
  const float* feat = (const float*)d_in[0];
  const int* posm   = (const int*)d_in[1];
  const int* negm   = (const int*)d_in[2];
  float* out = (float*)d_out;

  char* ws = (char*)d_ws;
  unsigned short* fnb = (unsigned short*)ws;                 // 8 MB
  float* Spos = (float*)(ws + (size_t)8 * 1024 * 1024);
  float* Sneg = Spos + NN;
  float* Pcnt = Sneg + NN;

  normalize_kernel<<<NN / 4, 256, 0, stream>>>(feat, fnb, Spos);
  fused_kernel<<<2080, 256, 0, stream>>>(fnb, posm, negm, Spos, Sneg, Pcnt);
  finalize_kernel<<<1, 256, 0, stream>>>(Spos, Sneg, Pcnt, out);
}